// Round 1
// baseline (668.209 us; speedup 1.0000x reference)
//
#include <hip/hip_runtime.h>
#include <hip/hip_bf16.h>

// Problem constants (B=1, N=256, C=128, H=4, CH=32)
#define NPOS 65536          // 256*256 pair positions
#define NSEQ 256
#define CDIM 128
#define NHEAD 4
#define CHDIM 32
#define ATT_SCALE 0.17677669529663687f  // 1/sqrt(32)

// ---------------------------------------------------------------------------
// Kernel A: LayerNorm + projections q,k,v,g (sigmoid-gated) + pair bias.
// One block = 32 consecutive positions. bias written transposed [h][y][x]
// (y = key position, x = query position) for coalesced reads in attention.
// ---------------------------------------------------------------------------
__global__ __launch_bounds__(256) void k_lnproj(
    const float* __restrict__ z, const float* __restrict__ lnw,
    const float* __restrict__ lnb,
    const float* __restrict__ Wq, const float* __restrict__ Wk,
    const float* __restrict__ Wv, const float* __restrict__ Wb,
    const float* __restrict__ Wg, const float* __restrict__ bg,
    float* __restrict__ q_o, float* __restrict__ k_o,
    float* __restrict__ v_o, float* __restrict__ g_o,
    float* __restrict__ bT)
{
    __shared__ __align__(16) float zn[32][132];   // padded: stride 132 floats
    __shared__ __align__(16) float wt[64][129];   // padded: stride 129 floats
    const int tid = threadIdx.x;
    const long p0 = (long)blockIdx.x * 32;

    // ---- stage 32 rows of z (contiguous 4096 floats) ----
    const float* zbase = z + p0 * CDIM;
#pragma unroll
    for (int it = 0; it < 4; ++it) {
        int f = (it * 256 + tid) * 4;
        float4 x4 = *(const float4*)(zbase + f);
        int r = f >> 7, c = f & 127;
        *(float4*)&zn[r][c] = x4;
    }
    __syncthreads();

    // ---- LayerNorm: 8 threads per row ----
    {
        int r = tid >> 3, sub = tid & 7, c0 = sub * 16;
        float s1 = 0.f, s2 = 0.f;
#pragma unroll
        for (int m = 0; m < 4; ++m) {
            float4 x4 = *(float4*)&zn[r][c0 + 4 * m];
            s1 += x4.x + x4.y + x4.z + x4.w;
            s2 += x4.x * x4.x + x4.y * x4.y + x4.z * x4.z + x4.w * x4.w;
        }
#pragma unroll
        for (int off = 1; off < 8; off <<= 1) {
            s1 += __shfl_xor(s1, off);
            s2 += __shfl_xor(s2, off);
        }
        float mu = s1 * 0.0078125f;
        float inv = rsqrtf(s2 * 0.0078125f - mu * mu + 1e-5f);
#pragma unroll
        for (int m = 0; m < 16; ++m) {
            int c = c0 + m;
            zn[r][c] = (zn[r][c] - mu) * inv * lnw[c] + lnb[c];
        }
    }
    __syncthreads();

    // ---- pair bias: 32 rows x 4 heads (threads 0..127) ----
    if (tid < 128) {
        int r = tid >> 2, h3 = tid & 3;
        float acc = 0.f;
#pragma unroll 8
        for (int k4 = 0; k4 < 32; ++k4) {
            float4 w4 = *(const float4*)(Wb + h3 * CDIM + k4 * 4);
            float4 z4 = *(const float4*)&zn[r][k4 * 4];
            acc += z4.x * w4.x + z4.y * w4.y + z4.z * w4.z + z4.w * w4.w;
        }
        long p = p0 + r;
        int x = (int)(p >> 8), y = (int)(p & 255);
        bT[h3 * 65536 + y * 256 + x] = acc;
    }

    // ---- 4 projection matrices, 2 column-tiles of 64 each ----
    const float* Ws[4] = {Wq, Wk, Wv, Wg};
    float* Os[4] = {q_o, k_o, v_o, g_o};
    for (int wsel = 0; wsel < 4; ++wsel) {
        const float* __restrict__ W = Ws[wsel];
        float* __restrict__ O = Os[wsel];
        for (int tile = 0; tile < 2; ++tile) {
            __syncthreads();   // protect wt reuse
#pragma unroll
            for (int it = 0; it < 8; ++it) {
                int f = (it * 256 + tid) * 4;
                float4 w4 = *(const float4*)(W + tile * 8192 + f);
                int r = f >> 7, c = f & 127;
                wt[r][c + 0] = w4.x; wt[r][c + 1] = w4.y;
                wt[r][c + 2] = w4.z; wt[r][c + 3] = w4.w;
            }
            __syncthreads();
            const int cl = tid & 63, rg = tid >> 6;
            float acc[8] = {0.f, 0.f, 0.f, 0.f, 0.f, 0.f, 0.f, 0.f};
#pragma unroll 4
            for (int k4 = 0; k4 < 32; ++k4) {
                float w0 = wt[cl][k4 * 4 + 0];
                float w1 = wt[cl][k4 * 4 + 1];
                float w2 = wt[cl][k4 * 4 + 2];
                float w3 = wt[cl][k4 * 4 + 3];
#pragma unroll
                for (int m = 0; m < 8; ++m) {
                    float4 z4 = *(float4*)&zn[rg * 8 + m][k4 * 4];
                    acc[m] += z4.x * w0 + z4.y * w1 + z4.z * w2 + z4.w * w3;
                }
            }
            int c = tile * 64 + cl;
            float bgc = (wsel == 3) ? bg[c] : 0.f;
#pragma unroll
            for (int m = 0; m < 8; ++m) {
                float vv = acc[m];
                if (wsel == 3) vv = 1.0f / (1.0f + __expf(-(vv + bgc)));
                O[(p0 + rg * 8 + m) * CDIM + c] = vv;
            }
        }
    }
}

// ---------------------------------------------------------------------------
// Kernel B: attention for one (head h, row i). 256 threads = 256 queries j.
// Online softmax over 256 keys in two 128-key LDS tiles. Gate fused.
// Output written in-place over q (each thread reads its own q first).
// ---------------------------------------------------------------------------
__global__ __launch_bounds__(256) void k_attn(
    float* __restrict__ q_ws, const float* __restrict__ k_ws,
    const float* __restrict__ v_ws, const float* __restrict__ g_ws,
    const float* __restrict__ bT, const float* __restrict__ pm)
{
    __shared__ __align__(16) float Ksh[128][40];
    __shared__ __align__(16) float Vsh[128][40];
    const int tid = threadIdx.x;
    const int h = blockIdx.x & 3;
    const int i = blockIdx.x >> 2;
    const int j = tid;

    // load q for this query into registers
    float qreg[32];
    const int qbase = (i * 256 + j) * CDIM + h * 32;
#pragma unroll
    for (int d4 = 0; d4 < 8; ++d4) {
        float4 x4 = *(const float4*)(q_ws + qbase + d4 * 4);
        qreg[d4 * 4 + 0] = x4.x; qreg[d4 * 4 + 1] = x4.y;
        qreg[d4 * 4 + 2] = x4.z; qreg[d4 * 4 + 3] = x4.w;
    }
    const float pmj = pm[i * 256 + j];

    float m = -INFINITY, l = 0.f;
    float o[32];
#pragma unroll
    for (int d = 0; d < 32; ++d) o[d] = 0.f;

    for (int kt = 0; kt < 2; ++kt) {
        __syncthreads();
        // stage 128 keys of K and V
#pragma unroll
        for (int it = 0; it < 4; ++it) {
            int idx = it * 256 + tid;
            int row = idx >> 3, d4 = (idx & 7) << 2;
            int goff = ((i * 256 + kt * 128 + row)) * CDIM + h * 32 + d4;
            *(float4*)&Ksh[row][d4] = *(const float4*)(k_ws + goff);
            *(float4*)&Vsh[row][d4] = *(const float4*)(v_ws + goff);
        }
        __syncthreads();

        for (int t8 = 0; t8 < 16; ++t8) {
            float s[8];
#pragma unroll
            for (int e = 0; e < 8; ++e) {
                int kk = t8 * 8 + e;
                int kg = kt * 128 + kk;
                float dot = 0.f;
#pragma unroll
                for (int d4 = 0; d4 < 8; ++d4) {
                    float4 k4 = *(const float4*)&Ksh[kk][d4 * 4];
                    dot += qreg[d4 * 4 + 0] * k4.x + qreg[d4 * 4 + 1] * k4.y +
                           qreg[d4 * 4 + 2] * k4.z + qreg[d4 * 4 + 3] * k4.w;
                }
                float bias = bT[h * 65536 + kg * 256 + j];
                float pmk = pm[i * 256 + kg];
                s[e] = (pmj * pmk > 0.5f) ? (dot * ATT_SCALE + bias) : -1e9f;
            }
            float tmax = s[0];
#pragma unroll
            for (int e = 1; e < 8; ++e) tmax = fmaxf(tmax, s[e]);
            float mnew = fmaxf(m, tmax);
            float resc = __expf(m - mnew);
            m = mnew;
            l *= resc;
#pragma unroll
            for (int d = 0; d < 32; ++d) o[d] *= resc;
#pragma unroll
            for (int e = 0; e < 8; ++e) {
                int kk = t8 * 8 + e;
                float p = __expf(s[e] - mnew);
                l += p;
#pragma unroll
                for (int d4 = 0; d4 < 8; ++d4) {
                    float4 v4 = *(const float4*)&Vsh[kk][d4 * 4];
                    o[d4 * 4 + 0] += p * v4.x; o[d4 * 4 + 1] += p * v4.y;
                    o[d4 * 4 + 2] += p * v4.z; o[d4 * 4 + 3] += p * v4.w;
                }
            }
        }
    }

    // normalize, gate, write back in place of q
    float invl = 1.0f / l;
#pragma unroll
    for (int d4 = 0; d4 < 8; ++d4) {
        float4 g4 = *(const float4*)(g_ws + qbase + d4 * 4);
        float4 r4;
        r4.x = o[d4 * 4 + 0] * invl * g4.x;
        r4.y = o[d4 * 4 + 1] * invl * g4.y;
        r4.z = o[d4 * 4 + 2] * invl * g4.z;
        r4.w = o[d4 * 4 + 3] * invl * g4.w;
        *(float4*)(q_ws + qbase + d4 * 4) = r4;
    }
}

// ---------------------------------------------------------------------------
// Kernel C: output projection  out = og @ Wo^T + bo
// ---------------------------------------------------------------------------
__global__ __launch_bounds__(256) void k_outproj(
    const float* __restrict__ og, const float* __restrict__ Wo,
    const float* __restrict__ bo, float* __restrict__ out)
{
    __shared__ __align__(16) float sx[32][132];
    __shared__ __align__(16) float wt[64][129];
    const int tid = threadIdx.x;
    const long p0 = (long)blockIdx.x * 32;

    const float* obase = og + p0 * CDIM;
#pragma unroll
    for (int it = 0; it < 4; ++it) {
        int f = (it * 256 + tid) * 4;
        float4 x4 = *(const float4*)(obase + f);
        int r = f >> 7, c = f & 127;
        *(float4*)&sx[r][c] = x4;
    }

    for (int tile = 0; tile < 2; ++tile) {
        __syncthreads();
#pragma unroll
        for (int it = 0; it < 8; ++it) {
            int f = (it * 256 + tid) * 4;
            float4 w4 = *(const float4*)(Wo + tile * 8192 + f);
            int r = f >> 7, c = f & 127;
            wt[r][c + 0] = w4.x; wt[r][c + 1] = w4.y;
            wt[r][c + 2] = w4.z; wt[r][c + 3] = w4.w;
        }
        __syncthreads();
        const int cl = tid & 63, rg = tid >> 6;
        float acc[8] = {0.f, 0.f, 0.f, 0.f, 0.f, 0.f, 0.f, 0.f};
#pragma unroll 4
        for (int k4 = 0; k4 < 32; ++k4) {
            float w0 = wt[cl][k4 * 4 + 0];
            float w1 = wt[cl][k4 * 4 + 1];
            float w2 = wt[cl][k4 * 4 + 2];
            float w3 = wt[cl][k4 * 4 + 3];
#pragma unroll
            for (int m = 0; m < 8; ++m) {
                float4 z4 = *(float4*)&sx[rg * 8 + m][k4 * 4];
                acc[m] += z4.x * w0 + z4.y * w1 + z4.z * w2 + z4.w * w3;
            }
        }
        int c = tile * 64 + cl;
        float boc = bo[c];
#pragma unroll
        for (int m = 0; m < 8; ++m) {
            out[(p0 + rg * 8 + m) * CDIM + c] = acc[m] + boc;
        }
    }
}

// ---------------------------------------------------------------------------
extern "C" void kernel_launch(void* const* d_in, const int* in_sizes, int n_in,
                              void* d_out, int out_size, void* d_ws, size_t ws_size,
                              hipStream_t stream) {
    const float* z   = (const float*)d_in[0];
    const float* pm  = (const float*)d_in[1];
    const float* lnw = (const float*)d_in[2];
    const float* lnb = (const float*)d_in[3];
    const float* Wq  = (const float*)d_in[4];
    const float* Wk  = (const float*)d_in[5];
    const float* Wv  = (const float*)d_in[6];
    const float* Wb  = (const float*)d_in[7];
    const float* Wg  = (const float*)d_in[8];
    const float* bg  = (const float*)d_in[9];
    const float* Wo  = (const float*)d_in[10];
    const float* bo  = (const float*)d_in[11];
    float* out = (float*)d_out;

    float* ws  = (float*)d_ws;
    float* q_o = ws;                     // 65536*128
    float* k_o = ws + 8388608;           // 65536*128
    float* v_o = ws + 16777216;          // 65536*128
    float* g_o = ws + 25165824;          // 65536*128
    float* bT  = ws + 33554432;          // 4*65536

    k_lnproj<<<2048, 256, 0, stream>>>(z, lnw, lnb, Wq, Wk, Wv, Wb, Wg, bg,
                                       q_o, k_o, v_o, g_o, bT);
    k_attn<<<1024, 256, 0, stream>>>(q_o, k_o, v_o, g_o, bT, pm);
    k_outproj<<<2048, 256, 0, stream>>>(q_o, Wo, bo, out);
}

// Round 2
// 399.702 us; speedup vs baseline: 1.6718x; 1.6718x over previous
//
#include <hip/hip_runtime.h>
#include <hip/hip_bf16.h>

// Problem constants (B=1, N=256, C=128, H=4, CH=32)
#define NSEQ 256
#define CDIM 128
#define ATT_SCALE 0.17677669529663687f   // 1/sqrt(32)
#define INV_SCALE 5.656854249492381f     // sqrt(32)

typedef __attribute__((ext_vector_type(8))) short short8v;
typedef __attribute__((ext_vector_type(4))) float f32x4;

__device__ __forceinline__ short f2bf(float f) {
    unsigned u = __builtin_bit_cast(unsigned, f);
    u = u + 0x7fffu + ((u >> 16) & 1u);   // RNE
    return (short)(u >> 16);
}

// ---------------------------------------------------------------------------
// Kernel A: LayerNorm + projections q,k,v,g (sigmoid-gated) + pair bias.
// One block = 32 consecutive positions. bias written transposed [h][key][query].
// ---------------------------------------------------------------------------
__global__ __launch_bounds__(256) void k_lnproj(
    const float* __restrict__ z, const float* __restrict__ lnw,
    const float* __restrict__ lnb,
    const float* __restrict__ Wq, const float* __restrict__ Wk,
    const float* __restrict__ Wv, const float* __restrict__ Wb,
    const float* __restrict__ Wg, const float* __restrict__ bg,
    float* __restrict__ q_o, float* __restrict__ k_o,
    float* __restrict__ v_o, float* __restrict__ g_o,
    float* __restrict__ bT)
{
    __shared__ __align__(16) float zn[32][132];
    __shared__ __align__(16) float wt[64][129];
    const int tid = threadIdx.x;
    const long p0 = (long)blockIdx.x * 32;

    const float* zbase = z + p0 * CDIM;
#pragma unroll
    for (int it = 0; it < 4; ++it) {
        int f = (it * 256 + tid) * 4;
        float4 x4 = *(const float4*)(zbase + f);
        int r = f >> 7, c = f & 127;
        *(float4*)&zn[r][c] = x4;
    }
    __syncthreads();

    {
        int r = tid >> 3, sub = tid & 7, c0 = sub * 16;
        float s1 = 0.f, s2 = 0.f;
#pragma unroll
        for (int m = 0; m < 4; ++m) {
            float4 x4 = *(float4*)&zn[r][c0 + 4 * m];
            s1 += x4.x + x4.y + x4.z + x4.w;
            s2 += x4.x * x4.x + x4.y * x4.y + x4.z * x4.z + x4.w * x4.w;
        }
#pragma unroll
        for (int off = 1; off < 8; off <<= 1) {
            s1 += __shfl_xor(s1, off);
            s2 += __shfl_xor(s2, off);
        }
        float mu = s1 * 0.0078125f;
        float inv = rsqrtf(s2 * 0.0078125f - mu * mu + 1e-5f);
#pragma unroll
        for (int m = 0; m < 16; ++m) {
            int c = c0 + m;
            zn[r][c] = (zn[r][c] - mu) * inv * lnw[c] + lnb[c];
        }
    }
    __syncthreads();

    if (tid < 128) {
        int r = tid >> 2, h3 = tid & 3;
        float acc = 0.f;
#pragma unroll 8
        for (int k4 = 0; k4 < 32; ++k4) {
            float4 w4 = *(const float4*)(Wb + h3 * CDIM + k4 * 4);
            float4 z4 = *(const float4*)&zn[r][k4 * 4];
            acc += z4.x * w4.x + z4.y * w4.y + z4.z * w4.z + z4.w * w4.w;
        }
        long p = p0 + r;
        int x = (int)(p >> 8), y = (int)(p & 255);
        bT[h3 * 65536 + y * 256 + x] = acc;
    }

    const float* Ws[4] = {Wq, Wk, Wv, Wg};
    float* Os[4] = {q_o, k_o, v_o, g_o};
    for (int wsel = 0; wsel < 4; ++wsel) {
        const float* __restrict__ W = Ws[wsel];
        float* __restrict__ O = Os[wsel];
        for (int tile = 0; tile < 2; ++tile) {
            __syncthreads();
#pragma unroll
            for (int it = 0; it < 8; ++it) {
                int f = (it * 256 + tid) * 4;
                float4 w4 = *(const float4*)(W + tile * 8192 + f);
                int r = f >> 7, c = f & 127;
                wt[r][c + 0] = w4.x; wt[r][c + 1] = w4.y;
                wt[r][c + 2] = w4.z; wt[r][c + 3] = w4.w;
            }
            __syncthreads();
            const int cl = tid & 63, rg = tid >> 6;
            float acc[8] = {0.f, 0.f, 0.f, 0.f, 0.f, 0.f, 0.f, 0.f};
#pragma unroll 4
            for (int k4 = 0; k4 < 32; ++k4) {
                float w0 = wt[cl][k4 * 4 + 0];
                float w1 = wt[cl][k4 * 4 + 1];
                float w2 = wt[cl][k4 * 4 + 2];
                float w3 = wt[cl][k4 * 4 + 3];
#pragma unroll
                for (int m = 0; m < 8; ++m) {
                    float4 z4 = *(float4*)&zn[rg * 8 + m][k4 * 4];
                    acc[m] += z4.x * w0 + z4.y * w1 + z4.z * w2 + z4.w * w3;
                }
            }
            int c = tile * 64 + cl;
            float bgc = (wsel == 3) ? bg[c] : 0.f;
#pragma unroll
            for (int m = 0; m < 8; ++m) {
                float vv = acc[m];
                if (wsel == 3) vv = 1.0f / (1.0f + __expf(-(vv + bgc)));
                O[(p0 + rg * 8 + m) * CDIM + c] = vv;
            }
        }
    }
}

// ---------------------------------------------------------------------------
// Kernel B (MFMA): attention for one (head h, row i). 4 waves, each wave owns
// 4 query-tiles of 16. S^T = K·Q^T via mfma_f32_16x16x32_bf16 (lane owns one
// query's 64 keys -> in-lane softmax + 2 shfl_xor). P->LDS (bf16, padded) ->
// PV MFMAs against V^T in LDS. bias fp32 folded into MFMA C-init as bias/scale.
// Output gated and written in place of q.
// ---------------------------------------------------------------------------
__global__ __launch_bounds__(256) void k_attn_mfma(
    float* __restrict__ q_ws, const float* __restrict__ k_ws,
    const float* __restrict__ v_ws, const float* __restrict__ g_ws,
    const float* __restrict__ bT, const float* __restrict__ pm)
{
    __shared__ __align__(16) short Ksh[256][40];    // keys x d, pad to 80B rows
    __shared__ __align__(16) short VTsh[32][264];   // d x keys, pad 264
    __shared__ __align__(16) short Psh[4][16][264]; // per-wave q x keys
    __shared__ float pmsh[256];

    const int tid  = threadIdx.x;
    const int lane = tid & 63;
    const int wave = tid >> 6;
    const int g    = lane >> 4;
    const int l15  = lane & 15;
    const int h = blockIdx.x & 3;
    const int i = blockIdx.x >> 2;
    const long base = (long)i * 256 * 128 + h * 32;

    pmsh[tid] = pm[i * 256 + tid];

    // stage K (bf16, row-major) and V^T (bf16, transposed)
#pragma unroll
    for (int pass = 0; pass < 8; ++pass) {
        int idx = pass * 256 + tid;
        int r = idx >> 3, c = (idx & 7) * 4;
        float4 kv = *(const float4*)(k_ws + base + (long)r * 128 + c);
        short4 ks;
        ks.x = f2bf(kv.x); ks.y = f2bf(kv.y); ks.z = f2bf(kv.z); ks.w = f2bf(kv.w);
        *(short4*)&Ksh[r][c] = ks;
        float4 vv = *(const float4*)(v_ws + base + (long)r * 128 + c);
        VTsh[c + 0][r] = f2bf(vv.x);
        VTsh[c + 1][r] = f2bf(vv.y);
        VTsh[c + 2][r] = f2bf(vv.z);
        VTsh[c + 3][r] = f2bf(vv.w);
    }
    __syncthreads();

    // per-lane key-mask bits: key(kt,r) = kt*16 + g*4 + r -> bit kt*4+r
    unsigned long long kmask = 0ull;
#pragma unroll
    for (int kt = 0; kt < 16; ++kt)
#pragma unroll
        for (int r = 0; r < 4; ++r)
            if (pmsh[kt * 16 + g * 4 + r] > 0.5f) kmask |= (1ull << (kt * 4 + r));

    const float* bbase = bT + h * 65536;

    for (int qi = 0; qi < 4; ++qi) {
        const int qt = wave * 4 + qi;
        const int q0 = qt * 16;
        const int ql = q0 + l15;

        // Q B-fragment: 8 consecutive fp32 -> bf16
        const float* qp = q_ws + base + (long)ql * 128 + g * 8;
        float4 qa = *(const float4*)qp;
        float4 qb = *(const float4*)(qp + 4);
        short8v bq;
        bq[0] = f2bf(qa.x); bq[1] = f2bf(qa.y); bq[2] = f2bf(qa.z); bq[3] = f2bf(qa.w);
        bq[4] = f2bf(qb.x); bq[5] = f2bf(qb.y); bq[6] = f2bf(qb.z); bq[7] = f2bf(qb.w);
        const float pmj = pmsh[ql];

        // S^T tiles: C-init = bias * INV_SCALE, then MFMA, then *ATT_SCALE
        f32x4 acc[16];
#pragma unroll
        for (int kt = 0; kt < 16; ++kt) {
            const float* bp = bbase + (kt * 16 + g * 4) * 256 + ql;
            f32x4 cini;
            cini[0] = bp[0]   * INV_SCALE;
            cini[1] = bp[256] * INV_SCALE;
            cini[2] = bp[512] * INV_SCALE;
            cini[3] = bp[768] * INV_SCALE;
            short8v ak = *(const short8v*)&Ksh[kt * 16 + l15][g * 8];
            acc[kt] = __builtin_amdgcn_mfma_f32_16x16x32_bf16(ak, bq, cini, 0, 0, 0);
        }

        // scale + mask + row max
        const bool rowok = pmj > 0.5f;
        float m = -INFINITY;
#pragma unroll
        for (int kt = 0; kt < 16; ++kt) {
#pragma unroll
            for (int r = 0; r < 4; ++r) {
                float sv = acc[kt][r] * ATT_SCALE;
                bool ok = rowok && ((kmask >> (kt * 4 + r)) & 1ull);
                sv = ok ? sv : -1e9f;
                acc[kt][r] = sv;
                m = fmaxf(m, sv);
            }
        }
        m = fmaxf(m, __shfl_xor(m, 16));
        m = fmaxf(m, __shfl_xor(m, 32));

        // exp + row sum
        float lsum = 0.f;
#pragma unroll
        for (int kt = 0; kt < 16; ++kt) {
#pragma unroll
            for (int r = 0; r < 4; ++r) {
                float p = __expf(acc[kt][r] - m);
                acc[kt][r] = p;
                lsum += p;
            }
        }
        lsum += __shfl_xor(lsum, 16);
        lsum += __shfl_xor(lsum, 32);
        const float linv_own = 1.0f / lsum;

        // P -> LDS (bf16), 4 consecutive keys per write
#pragma unroll
        for (int kt = 0; kt < 16; ++kt) {
            short4 pv;
            pv.x = f2bf(acc[kt][0]); pv.y = f2bf(acc[kt][1]);
            pv.z = f2bf(acc[kt][2]); pv.w = f2bf(acc[kt][3]);
            *(short4*)&Psh[wave][l15][kt * 16 + g * 4] = pv;
        }
        asm volatile("s_waitcnt lgkmcnt(0)" ::: "memory");

        // PV: O[q][d] over 8 k-chunks x 2 d-tiles
        f32x4 o0 = {0.f, 0.f, 0.f, 0.f}, o1 = {0.f, 0.f, 0.f, 0.f};
#pragma unroll
        for (int ch = 0; ch < 8; ++ch) {
            short8v ap  = *(const short8v*)&Psh[wave][l15][ch * 32 + g * 8];
            short8v bv0 = *(const short8v*)&VTsh[l15][ch * 32 + g * 8];
            short8v bv1 = *(const short8v*)&VTsh[16 + l15][ch * 32 + g * 8];
            o0 = __builtin_amdgcn_mfma_f32_16x16x32_bf16(ap, bv0, o0, 0, 0, 0);
            o1 = __builtin_amdgcn_mfma_f32_16x16x32_bf16(ap, bv1, o1, 0, 0, 0);
        }

        // epilogue: normalize, gate, store in place of q
#pragma unroll
        for (int r = 0; r < 4; ++r) {
            int qrow = g * 4 + r;
            float linv = __shfl(linv_own, qrow);
            long rowoff = base + (long)(q0 + qrow) * 128;
            float gv0 = g_ws[rowoff + l15];
            float gv1 = g_ws[rowoff + 16 + l15];
            q_ws[rowoff + l15]      = o0[r] * linv * gv0;
            q_ws[rowoff + 16 + l15] = o1[r] * linv * gv1;
        }
    }
}

// ---------------------------------------------------------------------------
// Kernel C: output projection  out = og @ Wo^T + bo
// ---------------------------------------------------------------------------
__global__ __launch_bounds__(256) void k_outproj(
    const float* __restrict__ og, const float* __restrict__ Wo,
    const float* __restrict__ bo, float* __restrict__ out)
{
    __shared__ __align__(16) float sx[32][132];
    __shared__ __align__(16) float wt[64][129];
    const int tid = threadIdx.x;
    const long p0 = (long)blockIdx.x * 32;

    const float* obase = og + p0 * CDIM;
#pragma unroll
    for (int it = 0; it < 4; ++it) {
        int f = (it * 256 + tid) * 4;
        float4 x4 = *(const float4*)(obase + f);
        int r = f >> 7, c = f & 127;
        *(float4*)&sx[r][c] = x4;
    }

    for (int tile = 0; tile < 2; ++tile) {
        __syncthreads();
#pragma unroll
        for (int it = 0; it < 8; ++it) {
            int f = (it * 256 + tid) * 4;
            float4 w4 = *(const float4*)(Wo + tile * 8192 + f);
            int r = f >> 7, c = f & 127;
            wt[r][c + 0] = w4.x; wt[r][c + 1] = w4.y;
            wt[r][c + 2] = w4.z; wt[r][c + 3] = w4.w;
        }
        __syncthreads();
        const int cl = tid & 63, rg = tid >> 6;
        float acc[8] = {0.f, 0.f, 0.f, 0.f, 0.f, 0.f, 0.f, 0.f};
#pragma unroll 4
        for (int k4 = 0; k4 < 32; ++k4) {
            float w0 = wt[cl][k4 * 4 + 0];
            float w1 = wt[cl][k4 * 4 + 1];
            float w2 = wt[cl][k4 * 4 + 2];
            float w3 = wt[cl][k4 * 4 + 3];
#pragma unroll
            for (int m = 0; m < 8; ++m) {
                float4 z4 = *(float4*)&sx[rg * 8 + m][k4 * 4];
                acc[m] += z4.x * w0 + z4.y * w1 + z4.z * w2 + z4.w * w3;
            }
        }
        int c = tile * 64 + cl;
        float boc = bo[c];
#pragma unroll
        for (int m = 0; m < 8; ++m) {
            out[(p0 + rg * 8 + m) * CDIM + c] = acc[m] + boc;
        }
    }
}

// ---------------------------------------------------------------------------
extern "C" void kernel_launch(void* const* d_in, const int* in_sizes, int n_in,
                              void* d_out, int out_size, void* d_ws, size_t ws_size,
                              hipStream_t stream) {
    const float* z   = (const float*)d_in[0];
    const float* pm  = (const float*)d_in[1];
    const float* lnw = (const float*)d_in[2];
    const float* lnb = (const float*)d_in[3];
    const float* Wq  = (const float*)d_in[4];
    const float* Wk  = (const float*)d_in[5];
    const float* Wv  = (const float*)d_in[6];
    const float* Wb  = (const float*)d_in[7];
    const float* Wg  = (const float*)d_in[8];
    const float* bg  = (const float*)d_in[9];
    const float* Wo  = (const float*)d_in[10];
    const float* bo  = (const float*)d_in[11];
    float* out = (float*)d_out;

    float* ws  = (float*)d_ws;
    float* q_o = ws;                     // 65536*128
    float* k_o = ws + 8388608;
    float* v_o = ws + 16777216;
    float* g_o = ws + 25165824;
    float* bT  = ws + 33554432;          // 4*65536

    k_lnproj<<<2048, 256, 0, stream>>>(z, lnw, lnb, Wq, Wk, Wv, Wb, Wg, bg,
                                       q_o, k_o, v_o, g_o, bT);
    k_attn_mfma<<<1024, 256, 0, stream>>>(q_o, k_o, v_o, g_o, bT, pm);
    k_outproj<<<2048, 256, 0, stream>>>(q_o, Wo, bo, out);
}

// Round 3
// 181.412 us; speedup vs baseline: 3.6834x; 2.2033x over previous
//
#include <hip/hip_runtime.h>
#include <hip/hip_bf16.h>

#define ATT_SCALE 0.17677669529663687f   // 1/sqrt(32)
#define INV_SCALE 5.656854249492381f     // sqrt(32)

typedef __attribute__((ext_vector_type(8))) short short8v;
typedef __attribute__((ext_vector_type(4))) float f32x4;

__device__ __forceinline__ short f2bf(float f) {
    unsigned u = __builtin_bit_cast(unsigned, f);
    u = u + 0x7fffu + ((u >> 16) & 1u);   // RNE
    return (short)(u >> 16);
}

// ---------------------------------------------------------------------------
// Kernel A (MFMA): LN + projections. Block = 128 positions, 4 waves.
// Wave tile = 64 rows x 64 cols (wr = wave>>1, wc = wave&1).
// zn bf16 in LDS [128][136]; W staged per-matrix bf16 [132][136] (rows 128-131
// hold Wb for the bias MFMA). q/k/v written bf16, g fp32 (sigmoid applied),
// bias fp32 transposed [h][j][i] for coalesced attn C-init reads.
// ---------------------------------------------------------------------------
__global__ __launch_bounds__(256, 2) void k_lnproj_mfma(
    const float* __restrict__ z, const float* __restrict__ lnw,
    const float* __restrict__ lnb,
    const float* __restrict__ Wq, const float* __restrict__ Wk,
    const float* __restrict__ Wv, const float* __restrict__ Wb,
    const float* __restrict__ Wg, const float* __restrict__ bg,
    unsigned short* __restrict__ q_o, unsigned short* __restrict__ k_o,
    unsigned short* __restrict__ v_o, float* __restrict__ g_o,
    float* __restrict__ bT)
{
    __shared__ __align__(16) short zn[128][136];
    __shared__ __align__(16) short wlds[132][136];

    const int tid  = threadIdx.x;
    const int lane = tid & 63;
    const int wave = tid >> 6;
    const int l15  = lane & 15;
    const int g    = lane >> 4;        // 0..3
    const int wr   = wave >> 1;        // row half
    const int wc   = wave & 1;         // col half
    const long p0  = (long)blockIdx.x * 128;

    // ---- LN phase: thread = (row, half-of-row) ----
    {
        const int r = tid >> 1, half = tid & 1;
        const float* zrow = z + (p0 + r) * 128 + half * 64;
        float4 xv[16];
        float s1 = 0.f, s2 = 0.f;
#pragma unroll
        for (int m = 0; m < 16; ++m) {
            xv[m] = *(const float4*)(zrow + m * 4);
            s1 += xv[m].x + xv[m].y + xv[m].z + xv[m].w;
            s2 += xv[m].x * xv[m].x + xv[m].y * xv[m].y +
                  xv[m].z * xv[m].z + xv[m].w * xv[m].w;
        }
        s1 += __shfl_xor(s1, 1);
        s2 += __shfl_xor(s2, 1);
        float mu  = s1 * 0.0078125f;
        float inv = rsqrtf(s2 * 0.0078125f - mu * mu + 1e-5f);
#pragma unroll
        for (int mm = 0; mm < 8; ++mm) {
            float4 a = xv[2 * mm], b = xv[2 * mm + 1];
            const float* wp = lnw + half * 64 + mm * 8;
            const float* bp = lnb + half * 64 + mm * 8;
            float4 w0 = *(const float4*)wp, w1 = *(const float4*)(wp + 4);
            float4 b0 = *(const float4*)bp, b1 = *(const float4*)(bp + 4);
            short8v s;
            s[0] = f2bf((a.x - mu) * inv * w0.x + b0.x);
            s[1] = f2bf((a.y - mu) * inv * w0.y + b0.y);
            s[2] = f2bf((a.z - mu) * inv * w0.z + b0.z);
            s[3] = f2bf((a.w - mu) * inv * w0.w + b0.w);
            s[4] = f2bf((b.x - mu) * inv * w1.x + b1.x);
            s[5] = f2bf((b.y - mu) * inv * w1.y + b1.y);
            s[6] = f2bf((b.z - mu) * inv * w1.z + b1.z);
            s[7] = f2bf((b.w - mu) * inv * w1.w + b1.w);
            *(short8v*)&zn[r][half * 64 + mm * 8] = s;
        }
    }
    __syncthreads();

    // ---- A fragments: held across all 4 matrices ----
    short8v afr[4][4];   // [rowtile][kstep]
#pragma unroll
    for (int rt = 0; rt < 4; ++rt)
#pragma unroll
        for (int ks = 0; ks < 4; ++ks)
            afr[rt][ks] = *(const short8v*)&zn[wr * 64 + rt * 16 + l15][ks * 32 + g * 8];

    const float* Ws[4] = {Wq, Wk, Wv, Wg};

    for (int wsel = 0; wsel < 4; ++wsel) {
        __syncthreads();   // previous wlds readers done
        const float* __restrict__ W = Ws[wsel];
#pragma unroll
        for (int it = 0; it < 8; ++it) {
            int idx = it * 256 + tid;
            int r = idx >> 4, cc = (idx & 15) * 8;
            float4 a = *(const float4*)(W + r * 128 + cc);
            float4 b = *(const float4*)(W + r * 128 + cc + 4);
            short8v s;
            s[0] = f2bf(a.x); s[1] = f2bf(a.y); s[2] = f2bf(a.z); s[3] = f2bf(a.w);
            s[4] = f2bf(b.x); s[5] = f2bf(b.y); s[6] = f2bf(b.z); s[7] = f2bf(b.w);
            *(short8v*)&wlds[r][cc] = s;
        }
        if (wsel == 0 && tid < 64) {
            int r4 = tid >> 4, cc = (tid & 15) * 8;
            float4 a = *(const float4*)(Wb + r4 * 128 + cc);
            float4 b = *(const float4*)(Wb + r4 * 128 + cc + 4);
            short8v s;
            s[0] = f2bf(a.x); s[1] = f2bf(a.y); s[2] = f2bf(a.z); s[3] = f2bf(a.w);
            s[4] = f2bf(b.x); s[5] = f2bf(b.y); s[6] = f2bf(b.z); s[7] = f2bf(b.w);
            *(short8v*)&wlds[128 + r4][cc] = s;
        }
        __syncthreads();

        short8v bfr[4][4];   // [coltile][kstep]
#pragma unroll
        for (int ct = 0; ct < 4; ++ct)
#pragma unroll
            for (int ks = 0; ks < 4; ++ks)
                bfr[ct][ks] = *(const short8v*)&wlds[wc * 64 + ct * 16 + l15][ks * 32 + g * 8];

        short8v wbfr[4];
        if (wsel == 0) {
#pragma unroll
            for (int ks = 0; ks < 4; ++ks)
                wbfr[ks] = *(const short8v*)&wlds[128 + (l15 & 3)][ks * 32 + g * 8];
        }

        f32x4 acc[4][4];
#pragma unroll
        for (int rt = 0; rt < 4; ++rt)
#pragma unroll
            for (int ct = 0; ct < 4; ++ct)
                acc[rt][ct] = (f32x4){0.f, 0.f, 0.f, 0.f};

#pragma unroll
        for (int ks = 0; ks < 4; ++ks)
#pragma unroll
            for (int rt = 0; rt < 4; ++rt)
#pragma unroll
                for (int ct = 0; ct < 4; ++ct)
                    acc[rt][ct] = __builtin_amdgcn_mfma_f32_16x16x32_bf16(
                        afr[rt][ks], bfr[ct][ks], acc[rt][ct], 0, 0, 0);

        if (wsel < 3) {
            unsigned short* __restrict__ O = (wsel == 0) ? q_o : (wsel == 1) ? k_o : v_o;
#pragma unroll
            for (int rt = 0; rt < 4; ++rt)
#pragma unroll
                for (int ct = 0; ct < 4; ++ct)
#pragma unroll
                    for (int r = 0; r < 4; ++r)
                        O[(p0 + wr * 64 + rt * 16 + g * 4 + r) * 128 +
                          wc * 64 + ct * 16 + l15] =
                            (unsigned short)f2bf(acc[rt][ct][r]);
        } else {
#pragma unroll
            for (int ct = 0; ct < 4; ++ct) {
                int c = wc * 64 + ct * 16 + l15;
                float bgc = bg[c];
#pragma unroll
                for (int rt = 0; rt < 4; ++rt)
#pragma unroll
                    for (int r = 0; r < 4; ++r) {
                        float val = acc[rt][ct][r] + bgc;
                        g_o[(p0 + wr * 64 + rt * 16 + g * 4 + r) * 128 + c] =
                            1.0f / (1.0f + __expf(-val));
                    }
            }
        }

        if (wsel == 0 && wc == 0) {
            f32x4 bacc[4];
#pragma unroll
            for (int rt = 0; rt < 4; ++rt) bacc[rt] = (f32x4){0.f, 0.f, 0.f, 0.f};
#pragma unroll
            for (int ks = 0; ks < 4; ++ks)
#pragma unroll
                for (int rt = 0; rt < 4; ++rt)
                    bacc[rt] = __builtin_amdgcn_mfma_f32_16x16x32_bf16(
                        afr[rt][ks], wbfr[ks], bacc[rt], 0, 0, 0);
            if (l15 < 4) {
#pragma unroll
                for (int rt = 0; rt < 4; ++rt)
#pragma unroll
                    for (int r = 0; r < 4; ++r) {
                        long p = p0 + wr * 64 + rt * 16 + g * 4 + r;
                        bT[l15 * 65536 + (int)(p & 255) * 256 + (int)(p >> 8)] =
                            bacc[rt][r];
                    }
            }
        }
    }
}

// ---------------------------------------------------------------------------
// Kernel B (MFMA): attention for one (head h, row i), bf16 q/k/v inputs.
// ---------------------------------------------------------------------------
__global__ __launch_bounds__(256) void k_attn_mfma(
    const unsigned short* __restrict__ q_ws, const unsigned short* __restrict__ k_ws,
    const unsigned short* __restrict__ v_ws, const float* __restrict__ g_ws,
    const float* __restrict__ bT, const float* __restrict__ pm,
    float* __restrict__ o_ws)
{
    __shared__ __align__(16) short Ksh[256][40];
    __shared__ __align__(16) short VTsh[32][264];
    __shared__ __align__(16) short Psh[4][16][264];
    __shared__ float pmsh[256];

    const int tid  = threadIdx.x;
    const int lane = tid & 63;
    const int wave = tid >> 6;
    const int g    = lane >> 4;
    const int l15  = lane & 15;
    const int h = blockIdx.x & 3;
    const int i = blockIdx.x >> 2;
    const long base = (long)i * 256 * 128 + h * 32;   // element offset

    pmsh[tid] = pm[i * 256 + tid];

    // stage K (row-major) and V^T (transposed), both bf16 already
#pragma unroll
    for (int pass = 0; pass < 4; ++pass) {
        int idx = pass * 256 + tid;          // 0..1023
        int r = idx >> 2, c8 = (idx & 3) * 8;
        short8v kv = *(const short8v*)(k_ws + base + (long)r * 128 + c8);
        *(short8v*)&Ksh[r][c8] = kv;
        short8v vv = *(const short8v*)(v_ws + base + (long)r * 128 + c8);
#pragma unroll
        for (int e = 0; e < 8; ++e) VTsh[c8 + e][r] = vv[e];
    }
    __syncthreads();

    unsigned long long kmask = 0ull;
#pragma unroll
    for (int kt = 0; kt < 16; ++kt)
#pragma unroll
        for (int r = 0; r < 4; ++r)
            if (pmsh[kt * 16 + g * 4 + r] > 0.5f) kmask |= (1ull << (kt * 4 + r));

    const float* bbase = bT + h * 65536;

    for (int qi = 0; qi < 4; ++qi) {
        const int qt = wave * 4 + qi;
        const int q0 = qt * 16;
        const int ql = q0 + l15;

        short8v bq = *(const short8v*)(q_ws + base + (long)ql * 128 + g * 8);
        const float pmj = pmsh[ql];

        f32x4 acc[16];
#pragma unroll
        for (int kt = 0; kt < 16; ++kt) {
            const float* bp = bbase + (kt * 16 + g * 4) * 256 + ql;
            f32x4 cini;
            cini[0] = bp[0]   * INV_SCALE;
            cini[1] = bp[256] * INV_SCALE;
            cini[2] = bp[512] * INV_SCALE;
            cini[3] = bp[768] * INV_SCALE;
            short8v ak = *(const short8v*)&Ksh[kt * 16 + l15][g * 8];
            acc[kt] = __builtin_amdgcn_mfma_f32_16x16x32_bf16(ak, bq, cini, 0, 0, 0);
        }

        const bool rowok = pmj > 0.5f;
        float m = -INFINITY;
#pragma unroll
        for (int kt = 0; kt < 16; ++kt) {
#pragma unroll
            for (int r = 0; r < 4; ++r) {
                float sv = acc[kt][r] * ATT_SCALE;
                bool ok = rowok && ((kmask >> (kt * 4 + r)) & 1ull);
                sv = ok ? sv : -1e9f;
                acc[kt][r] = sv;
                m = fmaxf(m, sv);
            }
        }
        m = fmaxf(m, __shfl_xor(m, 16));
        m = fmaxf(m, __shfl_xor(m, 32));

        float lsum = 0.f;
#pragma unroll
        for (int kt = 0; kt < 16; ++kt) {
#pragma unroll
            for (int r = 0; r < 4; ++r) {
                float p = __expf(acc[kt][r] - m);
                acc[kt][r] = p;
                lsum += p;
            }
        }
        lsum += __shfl_xor(lsum, 16);
        lsum += __shfl_xor(lsum, 32);
        const float linv_own = 1.0f / lsum;

#pragma unroll
        for (int kt = 0; kt < 16; ++kt) {
            short4 pv;
            pv.x = f2bf(acc[kt][0]); pv.y = f2bf(acc[kt][1]);
            pv.z = f2bf(acc[kt][2]); pv.w = f2bf(acc[kt][3]);
            *(short4*)&Psh[wave][l15][kt * 16 + g * 4] = pv;
        }
        asm volatile("s_waitcnt lgkmcnt(0)" ::: "memory");

        f32x4 o0 = {0.f, 0.f, 0.f, 0.f}, o1 = {0.f, 0.f, 0.f, 0.f};
#pragma unroll
        for (int ch = 0; ch < 8; ++ch) {
            short8v ap  = *(const short8v*)&Psh[wave][l15][ch * 32 + g * 8];
            short8v bv0 = *(const short8v*)&VTsh[l15][ch * 32 + g * 8];
            short8v bv1 = *(const short8v*)&VTsh[16 + l15][ch * 32 + g * 8];
            o0 = __builtin_amdgcn_mfma_f32_16x16x32_bf16(ap, bv0, o0, 0, 0, 0);
            o1 = __builtin_amdgcn_mfma_f32_16x16x32_bf16(ap, bv1, o1, 0, 0, 0);
        }

#pragma unroll
        for (int r = 0; r < 4; ++r) {
            int qrow = g * 4 + r;
            float linv = __shfl(linv_own, qrow);
            long rowoff = base + (long)(q0 + qrow) * 128;
            float gv0 = g_ws[rowoff + l15];
            float gv1 = g_ws[rowoff + 16 + l15];
            o_ws[rowoff + l15]      = o0[r] * linv * gv0;
            o_ws[rowoff + 16 + l15] = o1[r] * linv * gv1;
        }
    }
}

// ---------------------------------------------------------------------------
// Kernel C: output projection  out = o @ Wo^T + bo  (fp32, unchanged)
// ---------------------------------------------------------------------------
__global__ __launch_bounds__(256) void k_outproj(
    const float* __restrict__ og, const float* __restrict__ Wo,
    const float* __restrict__ bo, float* __restrict__ out)
{
    __shared__ __align__(16) float sx[32][132];
    __shared__ __align__(16) float wt[64][129];
    const int tid = threadIdx.x;
    const long p0 = (long)blockIdx.x * 32;

    const float* obase = og + p0 * 128;
#pragma unroll
    for (int it = 0; it < 4; ++it) {
        int f = (it * 256 + tid) * 4;
        float4 x4 = *(const float4*)(obase + f);
        int r = f >> 7, c = f & 127;
        *(float4*)&sx[r][c] = x4;
    }

    for (int tile = 0; tile < 2; ++tile) {
        __syncthreads();
#pragma unroll
        for (int it = 0; it < 8; ++it) {
            int f = (it * 256 + tid) * 4;
            float4 w4 = *(const float4*)(Wo + tile * 8192 + f);
            int r = f >> 7, c = f & 127;
            wt[r][c + 0] = w4.x; wt[r][c + 1] = w4.y;
            wt[r][c + 2] = w4.z; wt[r][c + 3] = w4.w;
        }
        __syncthreads();
        const int cl = tid & 63, rg = tid >> 6;
        float acc[8] = {0.f, 0.f, 0.f, 0.f, 0.f, 0.f, 0.f, 0.f};
#pragma unroll 4
        for (int k4 = 0; k4 < 32; ++k4) {
            float w0 = wt[cl][k4 * 4 + 0];
            float w1 = wt[cl][k4 * 4 + 1];
            float w2 = wt[cl][k4 * 4 + 2];
            float w3 = wt[cl][k4 * 4 + 3];
#pragma unroll
            for (int m = 0; m < 8; ++m) {
                float4 z4 = *(float4*)&sx[rg * 8 + m][k4 * 4];
                acc[m] += z4.x * w0 + z4.y * w1 + z4.z * w2 + z4.w * w3;
            }
        }
        int c = tile * 64 + cl;
        float boc = bo[c];
#pragma unroll
        for (int m = 0; m < 8; ++m) {
            out[(p0 + rg * 8 + m) * 128 + c] = acc[m] + boc;
        }
    }
}

// ---------------------------------------------------------------------------
extern "C" void kernel_launch(void* const* d_in, const int* in_sizes, int n_in,
                              void* d_out, int out_size, void* d_ws, size_t ws_size,
                              hipStream_t stream) {
    const float* z   = (const float*)d_in[0];
    const float* pm  = (const float*)d_in[1];
    const float* lnw = (const float*)d_in[2];
    const float* lnb = (const float*)d_in[3];
    const float* Wq  = (const float*)d_in[4];
    const float* Wk  = (const float*)d_in[5];
    const float* Wv  = (const float*)d_in[6];
    const float* Wb  = (const float*)d_in[7];
    const float* Wg  = (const float*)d_in[8];
    const float* bg  = (const float*)d_in[9];
    const float* Wo  = (const float*)d_in[10];
    const float* bo  = (const float*)d_in[11];
    float* out = (float*)d_out;

    unsigned short* qb = (unsigned short*)d_ws;   // 8388608 bf16
    unsigned short* kb = qb + 8388608;
    unsigned short* vb = kb + 8388608;
    float* gws = (float*)(vb + 8388608);          // 8388608 fp32
    float* bTw = gws + 8388608;                   // 262144 fp32
    float* ows = bTw + 262144;                    // 8388608 fp32

    k_lnproj_mfma<<<512, 256, 0, stream>>>(z, lnw, lnb, Wq, Wk, Wv, Wb, Wg, bg,
                                           qb, kb, vb, gws, bTw);
    k_attn_mfma<<<1024, 256, 0, stream>>>(qb, kb, vb, gws, bTw, pm, ows);
    k_outproj<<<2048, 256, 0, stream>>>(ows, Wo, bo, out);
}

// Round 4
// 127.400 us; speedup vs baseline: 5.2450x; 1.4240x over previous
//
#include <hip/hip_runtime.h>
#include <hip/hip_bf16.h>

#define ATT_SCALE 0.17677669529663687f   // 1/sqrt(32)
#define ZST 140   // zn row stride (shorts)
#define WST 140   // wlds row stride (shorts)

typedef __attribute__((ext_vector_type(8))) short short8v;
typedef __attribute__((ext_vector_type(4))) float f32x4;

__device__ __forceinline__ short f2bf(float f) {
    unsigned u = __builtin_bit_cast(unsigned, f);
    u = u + 0x7fffu + ((u >> 16) & 1u);   // RNE
    return (short)(u >> 16);
}
__device__ __forceinline__ float bf2f(short s) {
    unsigned u = ((unsigned)(unsigned short)s) << 16;
    return __builtin_bit_cast(float, u);
}

// ---------------------------------------------------------------------------
// Kernel A (MFMA): LN + projections. Block = 128 positions (one z-row chunk:
// x fixed, 128 consecutive y), 4 waves, wave tile 64x64.
// q scaled by ATT_SCALE at source. q/k/v written bf16 via LDS-staged coalesced
// 16B stores. g fp32 direct (64B-coalesced). bias natural layout bN[h][x][y].
// ---------------------------------------------------------------------------
__global__ __launch_bounds__(256, 2) void k_lnproj_mfma(
    const float* __restrict__ z, const float* __restrict__ lnw,
    const float* __restrict__ lnb,
    const float* __restrict__ Wq, const float* __restrict__ Wk,
    const float* __restrict__ Wv, const float* __restrict__ Wb,
    const float* __restrict__ Wg, const float* __restrict__ bg,
    unsigned short* __restrict__ q_o, unsigned short* __restrict__ k_o,
    unsigned short* __restrict__ v_o, float* __restrict__ g_o,
    float* __restrict__ bN)
{
    __shared__ __align__(16) short zn[128][ZST];    // LN result, then out-stage
    __shared__ __align__(16) short wlds[132][WST];

    const int tid  = threadIdx.x;
    const int lane = tid & 63;
    const int wave = tid >> 6;
    const int l15  = lane & 15;
    const int g    = lane >> 4;
    const int wr   = wave >> 1;
    const int wc   = wave & 1;
    const long p0  = (long)blockIdx.x * 128;
    const int xq   = (int)(p0 >> 8);      // fixed z-row for this block
    const int y0   = (int)(p0 & 255);     // 0 or 128

    // ---- LN: thread = (row, half) ----
    {
        const int r = tid >> 1, half = tid & 1;
        const float* zrow = z + (p0 + r) * 128 + half * 64;
        float4 xv[16];
        float s1 = 0.f, s2 = 0.f;
#pragma unroll
        for (int m = 0; m < 16; ++m) {
            xv[m] = *(const float4*)(zrow + m * 4);
            s1 += xv[m].x + xv[m].y + xv[m].z + xv[m].w;
            s2 += xv[m].x * xv[m].x + xv[m].y * xv[m].y +
                  xv[m].z * xv[m].z + xv[m].w * xv[m].w;
        }
        s1 += __shfl_xor(s1, 1);
        s2 += __shfl_xor(s2, 1);
        float mu  = s1 * 0.0078125f;
        float inv = rsqrtf(s2 * 0.0078125f - mu * mu + 1e-5f);
#pragma unroll
        for (int mm = 0; mm < 8; ++mm) {
            float4 a = xv[2 * mm], b = xv[2 * mm + 1];
            const float* wp = lnw + half * 64 + mm * 8;
            const float* bp = lnb + half * 64 + mm * 8;
            float4 w0 = *(const float4*)wp, w1 = *(const float4*)(wp + 4);
            float4 b0 = *(const float4*)bp, b1 = *(const float4*)(bp + 4);
            short8v s;
            s[0] = f2bf((a.x - mu) * inv * w0.x + b0.x);
            s[1] = f2bf((a.y - mu) * inv * w0.y + b0.y);
            s[2] = f2bf((a.z - mu) * inv * w0.z + b0.z);
            s[3] = f2bf((a.w - mu) * inv * w0.w + b0.w);
            s[4] = f2bf((b.x - mu) * inv * w1.x + b1.x);
            s[5] = f2bf((b.y - mu) * inv * w1.y + b1.y);
            s[6] = f2bf((b.z - mu) * inv * w1.z + b1.z);
            s[7] = f2bf((b.w - mu) * inv * w1.w + b1.w);
            *(short8v*)&zn[r][half * 64 + mm * 8] = s;
        }
    }
    __syncthreads();

    // ---- A fragments held for all matrices ----
    short8v afr[4][4];
#pragma unroll
    for (int rt = 0; rt < 4; ++rt)
#pragma unroll
        for (int ks = 0; ks < 4; ++ks)
            afr[rt][ks] = *(const short8v*)&zn[wr * 64 + rt * 16 + l15][ks * 32 + g * 8];

    const float* Ws[4] = {Wq, Wk, Wv, Wg};

    for (int wsel = 0; wsel < 4; ++wsel) {
        __syncthreads();   // prev wlds readers + prev copy-out done
        const float* __restrict__ W = Ws[wsel];
#pragma unroll
        for (int it = 0; it < 8; ++it) {
            int idx = it * 256 + tid;
            int r = idx >> 4, cc = (idx & 15) * 8;
            float4 a = *(const float4*)(W + r * 128 + cc);
            float4 b = *(const float4*)(W + r * 128 + cc + 4);
            short8v s;
            s[0] = f2bf(a.x); s[1] = f2bf(a.y); s[2] = f2bf(a.z); s[3] = f2bf(a.w);
            s[4] = f2bf(b.x); s[5] = f2bf(b.y); s[6] = f2bf(b.z); s[7] = f2bf(b.w);
            *(short8v*)&wlds[r][cc] = s;
        }
        if (wsel == 0 && tid < 64) {
            int r4 = tid >> 4, cc = (tid & 15) * 8;
            float4 a = *(const float4*)(Wb + r4 * 128 + cc);
            float4 b = *(const float4*)(Wb + r4 * 128 + cc + 4);
            short8v s;
            s[0] = f2bf(a.x); s[1] = f2bf(a.y); s[2] = f2bf(a.z); s[3] = f2bf(a.w);
            s[4] = f2bf(b.x); s[5] = f2bf(b.y); s[6] = f2bf(b.z); s[7] = f2bf(b.w);
            *(short8v*)&wlds[128 + r4][cc] = s;
        }
        __syncthreads();

        short8v bfr[4][4];
#pragma unroll
        for (int ct = 0; ct < 4; ++ct)
#pragma unroll
            for (int ks = 0; ks < 4; ++ks)
                bfr[ct][ks] = *(const short8v*)&wlds[wc * 64 + ct * 16 + l15][ks * 32 + g * 8];

        short8v wbfr[4];
        if (wsel == 0) {
#pragma unroll
            for (int ks = 0; ks < 4; ++ks)
                wbfr[ks] = *(const short8v*)&wlds[128 + (l15 & 3)][ks * 32 + g * 8];
        }

        f32x4 acc[4][4];
#pragma unroll
        for (int rt = 0; rt < 4; ++rt)
#pragma unroll
            for (int ct = 0; ct < 4; ++ct)
                acc[rt][ct] = (f32x4){0.f, 0.f, 0.f, 0.f};

#pragma unroll
        for (int ks = 0; ks < 4; ++ks)
#pragma unroll
            for (int rt = 0; rt < 4; ++rt)
#pragma unroll
                for (int ct = 0; ct < 4; ++ct)
                    acc[rt][ct] = __builtin_amdgcn_mfma_f32_16x16x32_bf16(
                        afr[rt][ks], bfr[ct][ks], acc[rt][ct], 0, 0, 0);

        if (wsel < 3) {
            // stage bf16 tile in LDS (conflict-free), then coalesced 16B writes
            const float sc = (wsel == 0) ? ATT_SCALE : 1.0f;
#pragma unroll
            for (int rt = 0; rt < 4; ++rt)
#pragma unroll
                for (int ct = 0; ct < 4; ++ct)
#pragma unroll
                    for (int r = 0; r < 4; ++r)
                        zn[wr * 64 + rt * 16 + g * 4 + r][wc * 64 + ct * 16 + l15] =
                            f2bf(acc[rt][ct][r] * sc);
            __syncthreads();
            unsigned short* __restrict__ O = (wsel == 0) ? q_o : (wsel == 1) ? k_o : v_o;
#pragma unroll
            for (int pass = 0; pass < 8; ++pass) {
                int idx = pass * 256 + tid;
                int row = idx >> 4, c8 = (idx & 15) * 8;
                *(short8v*)(O + (p0 + row) * 128 + c8) =
                    *(const short8v*)&zn[row][c8];
            }
        } else {
#pragma unroll
            for (int ct = 0; ct < 4; ++ct) {
                int c = wc * 64 + ct * 16 + l15;
                float bgc = bg[c];
#pragma unroll
                for (int rt = 0; rt < 4; ++rt)
#pragma unroll
                    for (int r = 0; r < 4; ++r) {
                        float val = acc[rt][ct][r] + bgc;
                        g_o[(p0 + wr * 64 + rt * 16 + g * 4 + r) * 128 + c] =
                            1.0f / (1.0f + __expf(-val));
                    }
            }
        }

        if (wsel == 0 && wc == 0) {
            f32x4 bacc[4];
#pragma unroll
            for (int rt = 0; rt < 4; ++rt) bacc[rt] = (f32x4){0.f, 0.f, 0.f, 0.f};
#pragma unroll
            for (int ks = 0; ks < 4; ++ks)
#pragma unroll
                for (int rt = 0; rt < 4; ++rt)
                    bacc[rt] = __builtin_amdgcn_mfma_f32_16x16x32_bf16(
                        afr[rt][ks], wbfr[ks], bacc[rt], 0, 0, 0);
            if (l15 < 4) {
                // natural layout: bN[h][x][y], contiguous in y
#pragma unroll
                for (int rt = 0; rt < 4; ++rt)
#pragma unroll
                    for (int r = 0; r < 4; ++r)
                        bN[l15 * 65536 + xq * 256 + y0 + wr * 64 + rt * 16 + g * 4 + r] =
                            bacc[rt][r];
            }
        }
    }
}

// ---------------------------------------------------------------------------
// Kernel B (MFMA): attention for one (head h, row i). q pre-scaled; bias in
// natural layout bN[h][query][key] -> float4 C-init.
// ---------------------------------------------------------------------------
__global__ __launch_bounds__(256) void k_attn_mfma(
    const unsigned short* __restrict__ q_ws, const unsigned short* __restrict__ k_ws,
    const unsigned short* __restrict__ v_ws, const float* __restrict__ g_ws,
    const float* __restrict__ bN, const float* __restrict__ pm,
    float* __restrict__ o_ws)
{
    __shared__ __align__(16) short Ksh[256][40];
    __shared__ __align__(16) short VTsh[32][264];
    __shared__ __align__(16) short Psh[4][16][264];
    __shared__ float pmsh[256];

    const int tid  = threadIdx.x;
    const int lane = tid & 63;
    const int wave = tid >> 6;
    const int g    = lane >> 4;
    const int l15  = lane & 15;
    const int h = blockIdx.x & 3;
    const int i = blockIdx.x >> 2;
    const long base = (long)i * 256 * 128 + h * 32;

    pmsh[tid] = pm[i * 256 + tid];

#pragma unroll
    for (int pass = 0; pass < 4; ++pass) {
        int idx = pass * 256 + tid;
        int r = idx >> 2, c8 = (idx & 3) * 8;
        short8v kv = *(const short8v*)(k_ws + base + (long)r * 128 + c8);
        *(short8v*)&Ksh[r][c8] = kv;
        short8v vv = *(const short8v*)(v_ws + base + (long)r * 128 + c8);
#pragma unroll
        for (int e = 0; e < 8; ++e) VTsh[c8 + e][r] = vv[e];
    }
    __syncthreads();

    unsigned long long kmask = 0ull;
#pragma unroll
    for (int kt = 0; kt < 16; ++kt)
#pragma unroll
        for (int r = 0; r < 4; ++r)
            if (pmsh[kt * 16 + g * 4 + r] > 0.5f) kmask |= (1ull << (kt * 4 + r));

    const float* bbase = bN + h * 65536;

    for (int qi = 0; qi < 4; ++qi) {
        const int qt = wave * 4 + qi;
        const int q0 = qt * 16;
        const int ql = q0 + l15;

        short8v bq = *(const short8v*)(q_ws + base + (long)ql * 128 + g * 8);
        const float pmj = pmsh[ql];

        f32x4 acc[16];
#pragma unroll
        for (int kt = 0; kt < 16; ++kt) {
            f32x4 cini = *(const f32x4*)(bbase + ql * 256 + kt * 16 + g * 4);
            short8v ak = *(const short8v*)&Ksh[kt * 16 + l15][g * 8];
            acc[kt] = __builtin_amdgcn_mfma_f32_16x16x32_bf16(ak, bq, cini, 0, 0, 0);
        }

        const bool rowok = pmj > 0.5f;
        float m = -INFINITY;
#pragma unroll
        for (int kt = 0; kt < 16; ++kt) {
#pragma unroll
            for (int r = 0; r < 4; ++r) {
                float sv = acc[kt][r];
                bool ok = rowok && ((kmask >> (kt * 4 + r)) & 1ull);
                sv = ok ? sv : -1e9f;
                acc[kt][r] = sv;
                m = fmaxf(m, sv);
            }
        }
        m = fmaxf(m, __shfl_xor(m, 16));
        m = fmaxf(m, __shfl_xor(m, 32));

        float lsum = 0.f;
#pragma unroll
        for (int kt = 0; kt < 16; ++kt) {
#pragma unroll
            for (int r = 0; r < 4; ++r) {
                float p = __expf(acc[kt][r] - m);
                acc[kt][r] = p;
                lsum += p;
            }
        }
        lsum += __shfl_xor(lsum, 16);
        lsum += __shfl_xor(lsum, 32);
        const float linv_own = 1.0f / lsum;

#pragma unroll
        for (int kt = 0; kt < 16; ++kt) {
            short4 pv;
            pv.x = f2bf(acc[kt][0]); pv.y = f2bf(acc[kt][1]);
            pv.z = f2bf(acc[kt][2]); pv.w = f2bf(acc[kt][3]);
            *(short4*)&Psh[wave][l15][kt * 16 + g * 4] = pv;
        }
        asm volatile("s_waitcnt lgkmcnt(0)" ::: "memory");

        f32x4 o0 = {0.f, 0.f, 0.f, 0.f}, o1 = {0.f, 0.f, 0.f, 0.f};
#pragma unroll
        for (int ch = 0; ch < 8; ++ch) {
            short8v ap  = *(const short8v*)&Psh[wave][l15][ch * 32 + g * 8];
            short8v bv0 = *(const short8v*)&VTsh[l15][ch * 32 + g * 8];
            short8v bv1 = *(const short8v*)&VTsh[16 + l15][ch * 32 + g * 8];
            o0 = __builtin_amdgcn_mfma_f32_16x16x32_bf16(ap, bv0, o0, 0, 0, 0);
            o1 = __builtin_amdgcn_mfma_f32_16x16x32_bf16(ap, bv1, o1, 0, 0, 0);
        }

#pragma unroll
        for (int r = 0; r < 4; ++r) {
            int qrow = g * 4 + r;
            float linv = __shfl(linv_own, qrow);
            long rowoff = base + (long)(q0 + qrow) * 128;
            float gv0 = g_ws[rowoff + l15];
            float gv1 = g_ws[rowoff + 16 + l15];
            o_ws[rowoff + l15]      = o0[r] * linv * gv0;
            o_ws[rowoff + 16 + l15] = o1[r] * linv * gv1;
        }
    }
}

// ---------------------------------------------------------------------------
// Kernel C (MFMA, hi/lo split): out = o @ Wo^T + bo, fp32-accurate.
// Block = 128 positions, wave tile 64x64. Wo split hi/lo in LDS once;
// x-fragments built from fp32 o on the fly. 3 MFMA passes (hh, hl, lh).
// ---------------------------------------------------------------------------
__global__ __launch_bounds__(256, 2) void k_outproj_mfma(
    const float* __restrict__ og, const float* __restrict__ Wo,
    const float* __restrict__ bo, float* __restrict__ out)
{
    __shared__ __align__(16) short whi[128][WST];
    __shared__ __align__(16) short wlo[128][WST];

    const int tid  = threadIdx.x;
    const int lane = tid & 63;
    const int wave = tid >> 6;
    const int l15  = lane & 15;
    const int g    = lane >> 4;
    const int wr   = wave >> 1;
    const int wc   = wave & 1;
    const long p0  = (long)blockIdx.x * 128;

    // stage Wo as hi/lo bf16
#pragma unroll
    for (int it = 0; it < 8; ++it) {
        int idx = it * 256 + tid;
        int r = idx >> 4, cc = (idx & 15) * 8;
        float4 a = *(const float4*)(Wo + r * 128 + cc);
        float4 b = *(const float4*)(Wo + r * 128 + cc + 4);
        float xs[8] = {a.x, a.y, a.z, a.w, b.x, b.y, b.z, b.w};
        short8v hi, lo;
#pragma unroll
        for (int e = 0; e < 8; ++e) {
            short hv = f2bf(xs[e]);
            hi[e] = hv;
            lo[e] = f2bf(xs[e] - bf2f(hv));
        }
        *(short8v*)&whi[r][cc] = hi;
        *(short8v*)&wlo[r][cc] = lo;
    }
    __syncthreads();

    f32x4 acc[4][4];
#pragma unroll
    for (int rt = 0; rt < 4; ++rt)
#pragma unroll
        for (int ct = 0; ct < 4; ++ct)
            acc[rt][ct] = (f32x4){0.f, 0.f, 0.f, 0.f};

#pragma unroll
    for (int ks = 0; ks < 4; ++ks) {
        short8v bh[4], bl[4];
#pragma unroll
        for (int ct = 0; ct < 4; ++ct) {
            bh[ct] = *(const short8v*)&whi[wc * 64 + ct * 16 + l15][ks * 32 + g * 8];
            bl[ct] = *(const short8v*)&wlo[wc * 64 + ct * 16 + l15][ks * 32 + g * 8];
        }
        short8v ah[4], al[4];
#pragma unroll
        for (int rt = 0; rt < 4; ++rt) {
            const float* ap = og + (p0 + wr * 64 + rt * 16 + l15) * 128 + ks * 32 + g * 8;
            float4 x0 = *(const float4*)ap;
            float4 x1 = *(const float4*)(ap + 4);
            float xs[8] = {x0.x, x0.y, x0.z, x0.w, x1.x, x1.y, x1.z, x1.w};
#pragma unroll
            for (int e = 0; e < 8; ++e) {
                short hv = f2bf(xs[e]);
                ah[rt][e] = hv;
                al[rt][e] = f2bf(xs[e] - bf2f(hv));
            }
        }
#pragma unroll
        for (int rt = 0; rt < 4; ++rt)
#pragma unroll
            for (int ct = 0; ct < 4; ++ct) {
                acc[rt][ct] = __builtin_amdgcn_mfma_f32_16x16x32_bf16(
                    ah[rt], bh[ct], acc[rt][ct], 0, 0, 0);
                acc[rt][ct] = __builtin_amdgcn_mfma_f32_16x16x32_bf16(
                    ah[rt], bl[ct], acc[rt][ct], 0, 0, 0);
                acc[rt][ct] = __builtin_amdgcn_mfma_f32_16x16x32_bf16(
                    al[rt], bh[ct], acc[rt][ct], 0, 0, 0);
            }
    }

#pragma unroll
    for (int ct = 0; ct < 4; ++ct) {
        int c = wc * 64 + ct * 16 + l15;
        float bv = bo[c];
#pragma unroll
        for (int rt = 0; rt < 4; ++rt)
#pragma unroll
            for (int r = 0; r < 4; ++r)
                out[(p0 + wr * 64 + rt * 16 + g * 4 + r) * 128 + c] =
                    acc[rt][ct][r] + bv;
    }
}

// ---------------------------------------------------------------------------
extern "C" void kernel_launch(void* const* d_in, const int* in_sizes, int n_in,
                              void* d_out, int out_size, void* d_ws, size_t ws_size,
                              hipStream_t stream) {
    const float* z   = (const float*)d_in[0];
    const float* pm  = (const float*)d_in[1];
    const float* lnw = (const float*)d_in[2];
    const float* lnb = (const float*)d_in[3];
    const float* Wq  = (const float*)d_in[4];
    const float* Wk  = (const float*)d_in[5];
    const float* Wv  = (const float*)d_in[6];
    const float* Wb  = (const float*)d_in[7];
    const float* Wg  = (const float*)d_in[8];
    const float* bg  = (const float*)d_in[9];
    const float* Wo  = (const float*)d_in[10];
    const float* bo  = (const float*)d_in[11];
    float* out = (float*)d_out;

    unsigned short* qb = (unsigned short*)d_ws;   // 8388608 bf16
    unsigned short* kb = qb + 8388608;
    unsigned short* vb = kb + 8388608;
    float* gws = (float*)(vb + 8388608);          // 8388608 fp32
    float* bNw = gws + 8388608;                   // 262144 fp32 (natural layout)
    float* ows = bNw + 262144;                    // 8388608 fp32

    k_lnproj_mfma<<<512, 256, 0, stream>>>(z, lnw, lnb, Wq, Wk, Wv, Wb, Wg, bg,
                                           qb, kb, vb, gws, bNw);
    k_attn_mfma<<<1024, 256, 0, stream>>>(qb, kb, vb, gws, bNw, pm, ows);
    k_outproj_mfma<<<512, 256, 0, stream>>>(ows, Wo, bo, out);
}

// Round 5
// 117.716 us; speedup vs baseline: 5.6764x; 1.0823x over previous
//
#include <hip/hip_runtime.h>
#include <hip/hip_bf16.h>

#define ATT_SCALE 0.17677669529663687f   // 1/sqrt(32)

typedef __attribute__((ext_vector_type(8))) short short8v;
typedef __attribute__((ext_vector_type(4))) float f32x4;

__device__ __forceinline__ short f2bf(float f) {
    unsigned u = __builtin_bit_cast(unsigned, f);
    u = u + 0x7fffu + ((u >> 16) & 1u);   // RNE
    return (short)(u >> 16);
}
__device__ __forceinline__ float bf2f(short s) {
    unsigned u = ((unsigned)(unsigned short)s) << 16;
    return __builtin_bit_cast(float, u);
}

// ---------------------------------------------------------------------------
// K0: one-time weight conversion. wbf = bf16{Wq*scale, Wk, Wv, Wg};
// wbbf = bf16 Wb; Wo -> hi/lo bf16 split (fp32-accurate 3-pass GEMM later).
// ---------------------------------------------------------------------------
__global__ __launch_bounds__(256) void k_wprep(
    const float* __restrict__ Wq, const float* __restrict__ Wk,
    const float* __restrict__ Wv, const float* __restrict__ Wg,
    const float* __restrict__ Wb, const float* __restrict__ Wo,
    unsigned short* __restrict__ wbf, unsigned short* __restrict__ wbbf,
    unsigned short* __restrict__ wohi, unsigned short* __restrict__ wolo)
{
    int idx = blockIdx.x * 256 + threadIdx.x;
    if (idx < 65536) {
        int m = idx >> 14, e = idx & 16383;
        float v;
        if (m == 0)      v = Wq[e] * ATT_SCALE;
        else if (m == 1) v = Wk[e];
        else if (m == 2) v = Wv[e];
        else             v = Wg[e];
        wbf[idx] = (unsigned short)f2bf(v);
    } else if (idx < 66048) {
        int e = idx - 65536;
        wbbf[e] = (unsigned short)f2bf(Wb[e]);
    } else if (idx < 82432) {
        int e = idx - 66048;
        float w = Wo[e];
        short hv = f2bf(w);
        wohi[e] = (unsigned short)hv;
        wolo[e] = (unsigned short)f2bf(w - bf2f(hv));
    }
}

// ---------------------------------------------------------------------------
// KA: LN + projections + bias. 512 threads = 8 waves, block = 128 positions.
// Wave tile 64 rows x 32 cols; wc (0..3) == head. One barrier total.
// B-fragments read directly from global bf16 weights (L2-hot).
// q/k/v written bf16 head-major [h][pos][32] via wave-private LDS staging.
// g fp32 head-major. bias fp32 natural [h][j][k].
// ---------------------------------------------------------------------------
__global__ __launch_bounds__(512, 4) void k_lnproj(
    const float* __restrict__ z, const float* __restrict__ lnw,
    const float* __restrict__ lnb,
    const unsigned short* __restrict__ wbf, const unsigned short* __restrict__ wbbf,
    const float* __restrict__ bg,
    unsigned short* __restrict__ q_o, unsigned short* __restrict__ k_o,
    unsigned short* __restrict__ v_o, float* __restrict__ g_o,
    float* __restrict__ bN)
{
    __shared__ __align__(16) short zn[128][136];       // 34.8 KB, persists
    __shared__ __align__(16) short wstg[8][32][40];    // 20.5 KB, wave-private

    const int tid  = threadIdx.x;
    const int lane = tid & 63;
    const int wave = tid >> 6;
    const int l15  = lane & 15;
    const int g    = lane >> 4;
    const int wr   = wave >> 2;       // row half (0..1)
    const int wc   = wave & 3;        // col quarter == head (0..3)
    const long p0  = (long)blockIdx.x * 128;

    // ---- LN: thread = (row, quarter) ----
    {
        const int r = tid >> 2, q4 = tid & 3;
        const float* zrow = z + (p0 + r) * 128 + q4 * 32;
        float4 xv[8];
        float s1 = 0.f, s2 = 0.f;
#pragma unroll
        for (int m = 0; m < 8; ++m) {
            xv[m] = *(const float4*)(zrow + m * 4);
            s1 += xv[m].x + xv[m].y + xv[m].z + xv[m].w;
            s2 += xv[m].x * xv[m].x + xv[m].y * xv[m].y +
                  xv[m].z * xv[m].z + xv[m].w * xv[m].w;
        }
        s1 += __shfl_xor(s1, 1); s2 += __shfl_xor(s2, 1);
        s1 += __shfl_xor(s1, 2); s2 += __shfl_xor(s2, 2);
        float mu  = s1 * 0.0078125f;
        float inv = rsqrtf(s2 * 0.0078125f - mu * mu + 1e-5f);
#pragma unroll
        for (int mm = 0; mm < 4; ++mm) {
            float4 a = xv[2 * mm], b = xv[2 * mm + 1];
            const float* wp = lnw + q4 * 32 + mm * 8;
            const float* bp = lnb + q4 * 32 + mm * 8;
            float4 w0 = *(const float4*)wp, w1 = *(const float4*)(wp + 4);
            float4 b0 = *(const float4*)bp, b1 = *(const float4*)(bp + 4);
            short8v s;
            s[0] = f2bf((a.x - mu) * inv * w0.x + b0.x);
            s[1] = f2bf((a.y - mu) * inv * w0.y + b0.y);
            s[2] = f2bf((a.z - mu) * inv * w0.z + b0.z);
            s[3] = f2bf((a.w - mu) * inv * w0.w + b0.w);
            s[4] = f2bf((b.x - mu) * inv * w1.x + b1.x);
            s[5] = f2bf((b.y - mu) * inv * w1.y + b1.y);
            s[6] = f2bf((b.z - mu) * inv * w1.z + b1.z);
            s[7] = f2bf((b.w - mu) * inv * w1.w + b1.w);
            *(short8v*)&zn[r][q4 * 32 + mm * 8] = s;
        }
    }
    __syncthreads();   // the only block-wide barrier

    // ---- pair bias (waves with wc==0; lanes l15<4 write head l15) ----
    if (wc == 0) {
        const unsigned short* wbp = wbbf + (l15 & 3) * 128;
        short8v wb[4];
#pragma unroll
        for (int ks = 0; ks < 4; ++ks)
            wb[ks] = *(const short8v*)(wbp + ks * 32 + g * 8);
        f32x4 bacc[4];
#pragma unroll
        for (int rt = 0; rt < 4; ++rt) bacc[rt] = (f32x4){0.f, 0.f, 0.f, 0.f};
#pragma unroll
        for (int ks = 0; ks < 4; ++ks)
#pragma unroll
            for (int rt = 0; rt < 4; ++rt) {
                short8v a = *(const short8v*)&zn[wr * 64 + rt * 16 + l15][ks * 32 + g * 8];
                bacc[rt] = __builtin_amdgcn_mfma_f32_16x16x32_bf16(a, wb[ks], bacc[rt], 0, 0, 0);
            }
        if (l15 < 4) {
            int xq = (int)(p0 >> 8), y0 = (int)(p0 & 255);
#pragma unroll
            for (int rt = 0; rt < 4; ++rt)
#pragma unroll
                for (int r = 0; r < 4; ++r)
                    bN[l15 * 65536 + xq * 256 + y0 + wr * 64 + rt * 16 + g * 4 + r] =
                        bacc[rt][r];
        }
    }

    // ---- 4 projection matrices, barrier-free ----
    for (int wsel = 0; wsel < 4; ++wsel) {
        const unsigned short* __restrict__ W = wbf + wsel * 16384;
        f32x4 acc[4][2];
#pragma unroll
        for (int rt = 0; rt < 4; ++rt) {
            acc[rt][0] = (f32x4){0.f, 0.f, 0.f, 0.f};
            acc[rt][1] = (f32x4){0.f, 0.f, 0.f, 0.f};
        }
#pragma unroll
        for (int ks = 0; ks < 4; ++ks) {
            short8v b0 = *(const short8v*)(W + (wc * 32 + l15) * 128 + ks * 32 + g * 8);
            short8v b1 = *(const short8v*)(W + (wc * 32 + 16 + l15) * 128 + ks * 32 + g * 8);
#pragma unroll
            for (int rt = 0; rt < 4; ++rt) {
                short8v a = *(const short8v*)&zn[wr * 64 + rt * 16 + l15][ks * 32 + g * 8];
                acc[rt][0] = __builtin_amdgcn_mfma_f32_16x16x32_bf16(a, b0, acc[rt][0], 0, 0, 0);
                acc[rt][1] = __builtin_amdgcn_mfma_f32_16x16x32_bf16(a, b1, acc[rt][1], 0, 0, 0);
            }
        }

        if (wsel == 3) {
            // sigmoid gate, fp32 head-major [h][pos][32]
#pragma unroll
            for (int ct = 0; ct < 2; ++ct) {
                float bgc = bg[wc * 32 + ct * 16 + l15];
#pragma unroll
                for (int rt = 0; rt < 4; ++rt)
#pragma unroll
                    for (int r = 0; r < 4; ++r) {
                        float val = acc[rt][ct][r] + bgc;
                        g_o[((long)wc * 65536 + p0 + wr * 64 + rt * 16 + g * 4 + r) * 32 +
                            ct * 16 + l15] = 1.0f / (1.0f + __expf(-val));
                    }
            }
        } else {
            unsigned short* __restrict__ O = (wsel == 0) ? q_o : (wsel == 1) ? k_o : v_o;
#pragma unroll
            for (int pair = 0; pair < 2; ++pair) {
                // stage 32 rows x 32 cols in wave-private scratch
#pragma unroll
                for (int rt2 = 0; rt2 < 2; ++rt2)
#pragma unroll
                    for (int ct = 0; ct < 2; ++ct)
#pragma unroll
                        for (int r = 0; r < 4; ++r)
                            wstg[wave][rt2 * 16 + g * 4 + r][ct * 16 + l15] =
                                f2bf(acc[pair * 2 + rt2][ct][r]);
                // coalesced copy-out (DS in-order per wave; compiler inserts waits)
#pragma unroll
                for (int ps = 0; ps < 2; ++ps) {
                    int idx = ps * 64 + lane;
                    int lr = idx >> 2, ch = (idx & 3) * 8;
                    short8v vv = *(const short8v*)&wstg[wave][lr][ch];
                    *(short8v*)(O + ((long)wc * 65536 + p0 + wr * 64 + pair * 32 + lr) * 32 + ch) = vv;
                }
            }
        }
    }
}

// ---------------------------------------------------------------------------
// KB: attention for one (head h, row i). Inputs head-major bf16 q/k/v,
// head-major fp32 g, natural fp32 bias. Output o fp32 natural [pos][128].
// ---------------------------------------------------------------------------
__global__ __launch_bounds__(256) void k_attn_mfma(
    const unsigned short* __restrict__ q_ws, const unsigned short* __restrict__ k_ws,
    const unsigned short* __restrict__ v_ws, const float* __restrict__ g_ws,
    const float* __restrict__ bN, const float* __restrict__ pm,
    float* __restrict__ o_ws)
{
    __shared__ __align__(16) short Ksh[256][40];
    __shared__ __align__(16) short VTsh[32][264];
    __shared__ __align__(16) short Psh[4][16][264];
    __shared__ float pmsh[256];

    const int tid  = threadIdx.x;
    const int lane = tid & 63;
    const int wave = tid >> 6;
    const int g    = lane >> 4;
    const int l15  = lane & 15;
    const int h = blockIdx.x & 3;
    const int i = blockIdx.x >> 2;
    const long hbase = ((long)h * 65536 + i * 256) * 32;   // head-major elem offset

    pmsh[tid] = pm[i * 256 + tid];

    // stage K (contiguous!) and V^T (transpose)
#pragma unroll
    for (int pass = 0; pass < 4; ++pass) {
        int idx = pass * 256 + tid;          // 0..1023
        int r = idx >> 2, c8 = (idx & 3) * 8;
        short8v kv = *(const short8v*)(k_ws + hbase + idx * 8);
        *(short8v*)&Ksh[r][c8] = kv;
        short8v vv = *(const short8v*)(v_ws + hbase + idx * 8);
#pragma unroll
        for (int e = 0; e < 8; ++e) VTsh[c8 + e][r] = vv[e];
    }
    __syncthreads();

    unsigned long long kmask = 0ull;
#pragma unroll
    for (int kt = 0; kt < 16; ++kt)
#pragma unroll
        for (int r = 0; r < 4; ++r)
            if (pmsh[kt * 16 + g * 4 + r] > 0.5f) kmask |= (1ull << (kt * 4 + r));

    const float* bbase = bN + h * 65536;

    for (int qi = 0; qi < 4; ++qi) {
        const int qt = wave * 4 + qi;
        const int q0 = qt * 16;
        const int ql = q0 + l15;

        short8v bq = *(const short8v*)(q_ws + hbase + (long)ql * 32 + g * 8);
        const float pmj = pmsh[ql];

        f32x4 acc[16];
#pragma unroll
        for (int kt = 0; kt < 16; ++kt) {
            f32x4 cini = *(const f32x4*)(bbase + ql * 256 + kt * 16 + g * 4);
            short8v ak = *(const short8v*)&Ksh[kt * 16 + l15][g * 8];
            acc[kt] = __builtin_amdgcn_mfma_f32_16x16x32_bf16(ak, bq, cini, 0, 0, 0);
        }

        const bool rowok = pmj > 0.5f;
        float m = -INFINITY;
#pragma unroll
        for (int kt = 0; kt < 16; ++kt) {
#pragma unroll
            for (int r = 0; r < 4; ++r) {
                float sv = acc[kt][r];
                bool ok = rowok && ((kmask >> (kt * 4 + r)) & 1ull);
                sv = ok ? sv : -1e9f;
                acc[kt][r] = sv;
                m = fmaxf(m, sv);
            }
        }
        m = fmaxf(m, __shfl_xor(m, 16));
        m = fmaxf(m, __shfl_xor(m, 32));

        float lsum = 0.f;
#pragma unroll
        for (int kt = 0; kt < 16; ++kt) {
#pragma unroll
            for (int r = 0; r < 4; ++r) {
                float p = __expf(acc[kt][r] - m);
                acc[kt][r] = p;
                lsum += p;
            }
        }
        lsum += __shfl_xor(lsum, 16);
        lsum += __shfl_xor(lsum, 32);
        const float linv_own = 1.0f / lsum;

#pragma unroll
        for (int kt = 0; kt < 16; ++kt) {
            short4 pv;
            pv.x = f2bf(acc[kt][0]); pv.y = f2bf(acc[kt][1]);
            pv.z = f2bf(acc[kt][2]); pv.w = f2bf(acc[kt][3]);
            *(short4*)&Psh[wave][l15][kt * 16 + g * 4] = pv;
        }
        asm volatile("s_waitcnt lgkmcnt(0)" ::: "memory");

        f32x4 o0 = {0.f, 0.f, 0.f, 0.f}, o1 = {0.f, 0.f, 0.f, 0.f};
#pragma unroll
        for (int ch = 0; ch < 8; ++ch) {
            short8v ap  = *(const short8v*)&Psh[wave][l15][ch * 32 + g * 8];
            short8v bv0 = *(const short8v*)&VTsh[l15][ch * 32 + g * 8];
            short8v bv1 = *(const short8v*)&VTsh[16 + l15][ch * 32 + g * 8];
            o0 = __builtin_amdgcn_mfma_f32_16x16x32_bf16(ap, bv0, o0, 0, 0, 0);
            o1 = __builtin_amdgcn_mfma_f32_16x16x32_bf16(ap, bv1, o1, 0, 0, 0);
        }

#pragma unroll
        for (int r = 0; r < 4; ++r) {
            int qrow = g * 4 + r;
            float linv = __shfl(linv_own, qrow);
            long grow = hbase + (long)(q0 + qrow) * 32;           // head-major g
            long orow = (long)(i * 256 + q0 + qrow) * 128 + h * 32; // natural o
            float gv0 = g_ws[grow + l15];
            float gv1 = g_ws[grow + 16 + l15];
            o_ws[orow + l15]      = o0[r] * linv * gv0;
            o_ws[orow + 16 + l15] = o1[r] * linv * gv1;
        }
    }
}

// ---------------------------------------------------------------------------
// KC: out = o @ Wo^T + bo via pre-split hi/lo bf16 MFMA (fp32-accurate).
// 512 threads, wave tile 64x32, no LDS, no barriers.
// ---------------------------------------------------------------------------
__global__ __launch_bounds__(512, 4) void k_outproj(
    const float* __restrict__ og, const unsigned short* __restrict__ wohi,
    const unsigned short* __restrict__ wolo, const float* __restrict__ bo,
    float* __restrict__ out)
{
    const int tid  = threadIdx.x;
    const int lane = tid & 63;
    const int wave = tid >> 6;
    const int l15  = lane & 15;
    const int g    = lane >> 4;
    const int wr   = wave >> 2;
    const int wc   = wave & 3;
    const long p0  = (long)blockIdx.x * 128;

    f32x4 acc[4][2];
#pragma unroll
    for (int rt = 0; rt < 4; ++rt) {
        acc[rt][0] = (f32x4){0.f, 0.f, 0.f, 0.f};
        acc[rt][1] = (f32x4){0.f, 0.f, 0.f, 0.f};
    }

#pragma unroll
    for (int ks = 0; ks < 4; ++ks) {
        const int wof = ks * 32 + g * 8;
        short8v bh0 = *(const short8v*)(wohi + (wc * 32 + l15) * 128 + wof);
        short8v bh1 = *(const short8v*)(wohi + (wc * 32 + 16 + l15) * 128 + wof);
        short8v bl0 = *(const short8v*)(wolo + (wc * 32 + l15) * 128 + wof);
        short8v bl1 = *(const short8v*)(wolo + (wc * 32 + 16 + l15) * 128 + wof);
#pragma unroll
        for (int rt = 0; rt < 4; ++rt) {
            const float* ap = og + (p0 + wr * 64 + rt * 16 + l15) * 128 + ks * 32 + g * 8;
            float4 x0 = *(const float4*)ap;
            float4 x1 = *(const float4*)(ap + 4);
            float xs[8] = {x0.x, x0.y, x0.z, x0.w, x1.x, x1.y, x1.z, x1.w};
            short8v ah, al;
#pragma unroll
            for (int e = 0; e < 8; ++e) {
                short hv = f2bf(xs[e]);
                ah[e] = hv;
                al[e] = f2bf(xs[e] - bf2f(hv));
            }
            acc[rt][0] = __builtin_amdgcn_mfma_f32_16x16x32_bf16(ah, bh0, acc[rt][0], 0, 0, 0);
            acc[rt][0] = __builtin_amdgcn_mfma_f32_16x16x32_bf16(ah, bl0, acc[rt][0], 0, 0, 0);
            acc[rt][0] = __builtin_amdgcn_mfma_f32_16x16x32_bf16(al, bh0, acc[rt][0], 0, 0, 0);
            acc[rt][1] = __builtin_amdgcn_mfma_f32_16x16x32_bf16(ah, bh1, acc[rt][1], 0, 0, 0);
            acc[rt][1] = __builtin_amdgcn_mfma_f32_16x16x32_bf16(ah, bl1, acc[rt][1], 0, 0, 0);
            acc[rt][1] = __builtin_amdgcn_mfma_f32_16x16x32_bf16(al, bh1, acc[rt][1], 0, 0, 0);
        }
    }

#pragma unroll
    for (int ct = 0; ct < 2; ++ct) {
        float bv = bo[wc * 32 + ct * 16 + l15];
#pragma unroll
        for (int rt = 0; rt < 4; ++rt)
#pragma unroll
            for (int r = 0; r < 4; ++r)
                out[(p0 + wr * 64 + rt * 16 + g * 4 + r) * 128 +
                    wc * 32 + ct * 16 + l15] = acc[rt][ct][r] + bv;
    }
}

// ---------------------------------------------------------------------------
extern "C" void kernel_launch(void* const* d_in, const int* in_sizes, int n_in,
                              void* d_out, int out_size, void* d_ws, size_t ws_size,
                              hipStream_t stream) {
    const float* z   = (const float*)d_in[0];
    const float* pm  = (const float*)d_in[1];
    const float* lnw = (const float*)d_in[2];
    const float* lnb = (const float*)d_in[3];
    const float* Wq  = (const float*)d_in[4];
    const float* Wk  = (const float*)d_in[5];
    const float* Wv  = (const float*)d_in[6];
    const float* Wb  = (const float*)d_in[7];
    const float* Wg  = (const float*)d_in[8];
    const float* bg  = (const float*)d_in[9];
    const float* Wo  = (const float*)d_in[10];
    const float* bo  = (const float*)d_in[11];
    float* out = (float*)d_out;

    unsigned short* wsS  = (unsigned short*)d_ws;
    unsigned short* wbf  = wsS;                   // 65536  (4x128x128 bf16)
    unsigned short* wbbf = wsS + 65536;           // 512
    unsigned short* wohi = wsS + 66048;           // 16384
    unsigned short* wolo = wsS + 82432;           // 16384
    unsigned short* qb   = wsS + 98816;           // 8388608 bf16 [4][65536][32]
    unsigned short* kb   = qb + 8388608;
    unsigned short* vb   = kb + 8388608;
    float* fbase = (float*)(wsS + 98816 + 3 * 8388608);
    float* gws = fbase;                           // 8388608 fp32 [4][65536][32]
    float* bNw = gws + 8388608;                   // 262144 fp32 [4][256][256]
    float* ows = bNw + 262144;                    // 8388608 fp32 [65536][128]

    k_wprep<<<322, 256, 0, stream>>>(Wq, Wk, Wv, Wg, Wb, Wo, wbf, wbbf, wohi, wolo);
    k_lnproj<<<512, 512, 0, stream>>>(z, lnw, lnb, wbf, wbbf, bg, qb, kb, vb, gws, bNw);
    k_attn_mfma<<<1024, 256, 0, stream>>>(qb, kb, vb, gws, bNw, pm, ows);
    k_outproj<<<512, 512, 0, stream>>>(ows, wohi, wolo, bo, out);
}